// Round 1
// baseline (588.070 us; speedup 1.0000x reference)
//
#include <hip/hip_runtime.h>
#include <math.h>

// Invariant Point Attention, b=1, n=512, dim=384, pdim=128, H=8, SK=SV=16, PK=4, PV=8
#define NTOK 512
#define DIM 384
#define PDIM 128
#define H 8

#define QKB_STRIDE 224   // 128 scalar + 96 point (global frame)
#define VB_STRIDE  320   // 128 scalar + 192 point (global frame)
#define RES_STRIDE 1408  // 128 scalar | 192 point-local | 64 norms | 1024 pair

static constexpr float SCALE_SCALAR = 0.14433756729740643f; // (3*16)^-0.5
static constexpr float SCALE_POINT  = 0.13608276348795434f; // (3*4*4.5)^-0.5
static constexpr float SCALE_PAIR   = 0.57735026918962580f; // 3^-0.5

__device__ __forceinline__ float f4get(const float4& v, int k) {
  return (k == 0) ? v.x : (k == 1) ? v.y : (k == 2) ? v.z : v.w;
}

// ---------------- Kernel 1: projections + frame transform ----------------
__global__ __launch_bounds__(256) void ipa_proj(
    const float* __restrict__ x, const float* __restrict__ rot, const float* __restrict__ trans,
    const float* __restrict__ Wsq, const float* __restrict__ Wsk, const float* __restrict__ Wsv,
    const float* __restrict__ Wpq, const float* __restrict__ Wpk, const float* __restrict__ Wpv,
    float* __restrict__ qB, float* __restrict__ kB, float* __restrict__ vB)
{
  const int i = blockIdx.x, tid = threadIdx.x;
  __shared__ float s_x[DIM];
  __shared__ float s_proj[768];
  __shared__ float s_R[9], s_T[3];

  for (int t = tid; t < DIM; t += 256) s_x[t] = x[i * DIM + t];
  if (tid < 9) s_R[tid] = rot[i * 9 + tid];
  if (tid < 3) s_T[tid] = trans[i * 3 + tid];
  __syncthreads();

#pragma unroll
  for (int r = 0; r < 3; ++r) {
    int c = tid + 256 * r;
    const float* W; int ncols, lc;
    if      (c < 128) { W = Wsq; ncols = 128; lc = c; }
    else if (c < 256) { W = Wsk; ncols = 128; lc = c - 128; }
    else if (c < 384) { W = Wsv; ncols = 128; lc = c - 256; }
    else if (c < 480) { W = Wpq; ncols = 96;  lc = c - 384; }
    else if (c < 576) { W = Wpk; ncols = 96;  lc = c - 480; }
    else              { W = Wpv; ncols = 192; lc = c - 576; }
    const float* wp = W + lc;
    float acc = 0.f;
#pragma unroll 4
    for (int k = 0; k < DIM; ++k) { acc += s_x[k] * (*wp); wp += ncols; }
    s_proj[c] = acc;
  }
  __syncthreads();

  if (tid < 128) {
    // point triples -> global frame:  g[r] = sum_c p[c] * R[c][r] + T[r]
    int t = tid, src; float* dst;
    if      (t < 32) { src = 384 + t * 3;        dst = qB + (size_t)i * QKB_STRIDE + 128 + t * 3; }
    else if (t < 64) { src = 480 + (t - 32) * 3; dst = kB + (size_t)i * QKB_STRIDE + 128 + (t - 32) * 3; }
    else             { src = 576 + (t - 64) * 3; dst = vB + (size_t)i * VB_STRIDE + 128 + (t - 64) * 3; }
    float px = s_proj[src], py = s_proj[src + 1], pz = s_proj[src + 2];
#pragma unroll
    for (int r = 0; r < 3; ++r)
      dst[r] = px * s_R[0 * 3 + r] + py * s_R[1 * 3 + r] + pz * s_R[2 * 3 + r] + s_T[r];
  } else {
    int j = tid - 128;
    qB[(size_t)i * QKB_STRIDE + j] = s_proj[j];
    kB[(size_t)i * QKB_STRIDE + j] = s_proj[128 + j];
    vB[(size_t)i * VB_STRIDE + j]  = s_proj[256 + j];
  }
}

// ---------------- Kernel 2: fused logits + softmax + aggregation ----------------
__global__ __launch_bounds__(256) void ipa_attn(
    const float* __restrict__ pair, const float* __restrict__ rot, const float* __restrict__ trans,
    const float* __restrict__ pw, const float* __restrict__ Wpair, const float* __restrict__ bpair,
    const float* __restrict__ qB, const float* __restrict__ kB, const float* __restrict__ vB,
    float* __restrict__ results)
{
  const int i = blockIdx.x, tid = threadIdx.x;

  __shared__ float s_attn[NTOK * 12];     // 24 KB  (logits, then exp values)
  __shared__ float s_wpair[PDIM * H];     // 4 KB   [d][h]
  __shared__ float s_qs[128];
  __shared__ float s_qp[96];
  __shared__ float s_red[4 * 1024];       // 16 KB  pass-C reduction
  __shared__ float s_res[RES_STRIDE];     // 5.5 KB
  __shared__ float s_ptsum[192];
  __shared__ float s_invl[H], s_coef[H], s_bp[H];
  __shared__ float s_R[9], s_T[3];

  for (int t = tid; t < PDIM * H; t += 256) s_wpair[t] = Wpair[t];
  if (tid < 224) {
    float v = qB[(size_t)i * QKB_STRIDE + tid];
    if (tid < 128) s_qs[tid] = v; else s_qp[tid - 128] = v;
  }
  if (tid < H) {
    s_coef[tid] = -0.5f * log1pf(expf(pw[tid])) * SCALE_POINT;  // softplus
    s_bp[tid]   = bpair[tid];
  }
  if (tid >= 32 && tid < 41) s_R[tid - 32] = rot[i * 9 + (tid - 32)];
  if (tid >= 48 && tid < 51) s_T[tid - 48] = trans[i * 3 + (tid - 48)];
  __syncthreads();

  // ---- Phase A: logits for j0 = tid, j1 = tid+256, all 8 heads ----
  {
    const int j0 = tid, j1 = tid + 256;
    const float4* pr0 = reinterpret_cast<const float4*>(pair + ((size_t)i * NTOK + j0) * PDIM);
    const float4* pr1 = reinterpret_cast<const float4*>(pair + ((size_t)i * NTOK + j1) * PDIM);

    float pa0[H] = {}, pa1[H] = {};
#pragma unroll 4
    for (int d4 = 0; d4 < 32; ++d4) {
      float4 a0 = pr0[d4], a1 = pr1[d4];
      const float4* wp = reinterpret_cast<const float4*>(&s_wpair[d4 * 32]);
#pragma unroll
      for (int dd = 0; dd < 4; ++dd) {
        float4 wA = wp[dd * 2], wB = wp[dd * 2 + 1];
        float x0 = f4get(a0, dd), x1 = f4get(a1, dd);
        pa0[0] += x0 * wA.x; pa0[1] += x0 * wA.y; pa0[2] += x0 * wA.z; pa0[3] += x0 * wA.w;
        pa0[4] += x0 * wB.x; pa0[5] += x0 * wB.y; pa0[6] += x0 * wB.z; pa0[7] += x0 * wB.w;
        pa1[0] += x1 * wA.x; pa1[1] += x1 * wA.y; pa1[2] += x1 * wA.z; pa1[3] += x1 * wA.w;
        pa1[4] += x1 * wB.x; pa1[5] += x1 * wB.y; pa1[6] += x1 * wB.z; pa1[7] += x1 * wB.w;
      }
    }

    float sa0[H] = {}, sa1[H] = {};
    const float4* q4  = reinterpret_cast<const float4*>(s_qs);
    const float4* k40 = reinterpret_cast<const float4*>(kB + (size_t)j0 * QKB_STRIDE);
    const float4* k41 = reinterpret_cast<const float4*>(kB + (size_t)j1 * QKB_STRIDE);
#pragma unroll 4
    for (int t4 = 0; t4 < 32; ++t4) {
      int h = t4 >> 2;
      float4 q = q4[t4], ka = k40[t4], kb = k41[t4];
      sa0[h] += q.x * ka.x + q.y * ka.y + q.z * ka.z + q.w * ka.w;
      sa1[h] += q.x * kb.x + q.y * kb.y + q.z * kb.z + q.w * kb.w;
    }

    float da0[H] = {}, da1[H] = {};
    const float4* qp4 = reinterpret_cast<const float4*>(s_qp);
#pragma unroll 3
    for (int t4 = 0; t4 < 24; ++t4) {
      int h = t4 / 3;
      float4 q = qp4[t4], ka = k40[32 + t4], kb = k41[32 + t4];
      float d;
      d = q.x - ka.x; da0[h] += d * d;  d = q.y - ka.y; da0[h] += d * d;
      d = q.z - ka.z; da0[h] += d * d;  d = q.w - ka.w; da0[h] += d * d;
      d = q.x - kb.x; da1[h] += d * d;  d = q.y - kb.y; da1[h] += d * d;
      d = q.z - kb.z; da1[h] += d * d;  d = q.w - kb.w; da1[h] += d * d;
    }

#pragma unroll
    for (int h = 0; h < H; ++h) {
      s_attn[j0 * 12 + h] = sa0[h] * SCALE_SCALAR + s_coef[h] * da0[h] + (pa0[h] + s_bp[h]) * SCALE_PAIR;
      s_attn[j1 * 12 + h] = sa1[h] * SCALE_SCALAR + s_coef[h] * da1[h] + (pa1[h] + s_bp[h]) * SCALE_PAIR;
    }
  }
  __syncthreads();

  // ---- Phase B: softmax per head (32 lanes per head) ----
  {
    int h = tid >> 5, l = tid & 31;
    float m = -1e30f;
#pragma unroll 4
    for (int k = 0; k < 16; ++k) m = fmaxf(m, s_attn[(l + 32 * k) * 12 + h]);
#pragma unroll
    for (int off = 16; off; off >>= 1) m = fmaxf(m, __shfl_xor(m, off, 32));
    float s = 0.f;
#pragma unroll 4
    for (int k = 0; k < 16; ++k) {
      int j = l + 32 * k;
      float e = __expf(s_attn[j * 12 + h] - m);
      s_attn[j * 12 + h] = e;
      s += e;
    }
#pragma unroll
    for (int off = 16; off; off >>= 1) s += __shfl_xor(s, off, 32);
    if (l == 0) s_invl[h] = 1.f / s;
  }
  __syncthreads();

  // ---- Phase C: res_pair = sum_j attn[h][j] * pair[i][j][:]  (re-read is L2-hot) ----
  {
    int g = tid >> 5, d4 = tid & 31;
    float4 acc[H];
#pragma unroll
    for (int h = 0; h < H; ++h) acc[h] = make_float4(0.f, 0.f, 0.f, 0.f);
    const float4* pbase = reinterpret_cast<const float4*>(pair + (size_t)i * NTOK * PDIM);
    int jbeg = g * 64;
    for (int j = jbeg; j < jbeg + 64; ++j) {
      float4 pv = pbase[j * 32 + d4];
      const float4* arow = reinterpret_cast<const float4*>(&s_attn[j * 12]);
      float4 aA = arow[0], aB = arow[1];
#define FMA4(A, S) { (A).x += (S) * pv.x; (A).y += (S) * pv.y; (A).z += (S) * pv.z; (A).w += (S) * pv.w; }
      FMA4(acc[0], aA.x) FMA4(acc[1], aA.y) FMA4(acc[2], aA.z) FMA4(acc[3], aA.w)
      FMA4(acc[4], aB.x) FMA4(acc[5], aB.y) FMA4(acc[6], aB.z) FMA4(acc[7], aB.w)
#undef FMA4
    }
    if (g < 4) {
#pragma unroll
      for (int h = 0; h < H; ++h)
        *reinterpret_cast<float4*>(&s_red[g * 1024 + h * 128 + d4 * 4]) = acc[h];
    }
    __syncthreads();
    if (g >= 4) {
      int gg = g - 4;
#pragma unroll
      for (int h = 0; h < H; ++h) {
        float4* p = reinterpret_cast<float4*>(&s_red[gg * 1024 + h * 128 + d4 * 4]);
        float4 v = *p;
        v.x += acc[h].x; v.y += acc[h].y; v.z += acc[h].z; v.w += acc[h].w;
        *p = v;
      }
    }
    __syncthreads();
    {
      int h = tid >> 5;
      float il = s_invl[h];
      float4 v0 = *reinterpret_cast<float4*>(&s_red[0 * 1024 + tid * 4]);
      float4 v1 = *reinterpret_cast<float4*>(&s_red[1 * 1024 + tid * 4]);
      float4 v2 = *reinterpret_cast<float4*>(&s_red[2 * 1024 + tid * 4]);
      float4 v3 = *reinterpret_cast<float4*>(&s_red[3 * 1024 + tid * 4]);
      float4 o;
      o.x = (v0.x + v1.x + v2.x + v3.x) * il;
      o.y = (v0.y + v1.y + v2.y + v3.y) * il;
      o.z = (v0.z + v1.z + v2.z + v3.z) * il;
      o.w = (v0.w + v1.w + v2.w + v3.w) * il;
      *reinterpret_cast<float4*>(&s_res[384 + tid * 4]) = o;
    }
  }
  __syncthreads();

  // ---- Phase D: v_s / v_p aggregation (320 outputs) ----
  {
    int o = tid;
    int h0 = (o < 128) ? (o >> 4) : ((o - 128) / 24);
    int o2 = tid + 256;
    int h1 = (tid < 64) ? ((o2 - 128) / 24) : 0;
    float acc0 = 0.f, acc1 = 0.f;
#pragma unroll 4
    for (int j = 0; j < NTOK; ++j) {
      float a0 = s_attn[j * 12 + h0];
      acc0 += a0 * vB[(size_t)j * VB_STRIDE + o];
      if (tid < 64) {  // wave-uniform branch
        float a1 = s_attn[j * 12 + h1];
        acc1 += a1 * vB[(size_t)j * VB_STRIDE + o2];
      }
    }
    acc0 *= s_invl[h0];
    if (o < 128) s_res[o] = acc0; else s_ptsum[o - 128] = acc0;
    if (tid < 64) { acc1 *= s_invl[h1]; s_ptsum[o2 - 128] = acc1; }
  }
  __syncthreads();

  // ---- Phase E: back to local frame + norms ----
  if (tid < 64) {
    int h = tid >> 3, p = tid & 7;
    int base = h * 24 + p * 3;
    float gx = s_ptsum[base]     - s_T[0];
    float gy = s_ptsum[base + 1] - s_T[1];
    float gz = s_ptsum[base + 2] - s_T[2];
    // local[r] = sum_c g[c] * R[r][c]
    float lx = gx * s_R[0] + gy * s_R[1] + gz * s_R[2];
    float ly = gx * s_R[3] + gy * s_R[4] + gz * s_R[5];
    float lz = gx * s_R[6] + gy * s_R[7] + gz * s_R[8];
    s_res[128 + base]     = lx;
    s_res[128 + base + 1] = ly;
    s_res[128 + base + 2] = lz;
    s_res[320 + h * 8 + p] = sqrtf(lx * lx + ly * ly + lz * lz + 1e-8f);
  }
  __syncthreads();

  // ---- Phase F: write result row ----
  {
    float4* dst = reinterpret_cast<float4*>(results + (size_t)i * RES_STRIDE);
    const float4* src = reinterpret_cast<const float4*>(s_res);
    for (int t = tid; t < RES_STRIDE / 4; t += 256) dst[t] = src[t];
  }
}

// ---------------- Kernel 3: out = results @ Wout + bout ----------------
__global__ __launch_bounds__(256) void ipa_out(
    const float* __restrict__ results, const float* __restrict__ Wout,
    const float* __restrict__ bout, float* __restrict__ out)
{
  const int ib = blockIdx.x, cb = blockIdx.y, tid = threadIdx.x;
  __shared__ float s_r[4 * RES_STRIDE];  // 22.5 KB
  __shared__ float s_w[64 * 128];        // 32 KB
  {
    const float4* src = reinterpret_cast<const float4*>(results + (size_t)ib * 4 * RES_STRIDE);
    float4* dst = reinterpret_cast<float4*>(s_r);
    for (int t = tid; t < 4 * RES_STRIDE / 4; t += 256) dst[t] = src[t];
  }
  int c = tid & 127, half = tid >> 7;
  const float* r0 = s_r + (half * 2 + 0) * RES_STRIDE;
  const float* r1 = s_r + (half * 2 + 1) * RES_STRIDE;
  float acc0 = 0.f, acc1 = 0.f;
  for (int k0 = 0; k0 < RES_STRIDE; k0 += 64) {
    __syncthreads();
    for (int t = tid; t < 64 * 32; t += 256) {
      int kk = t >> 5, c4 = t & 31;
      reinterpret_cast<float4*>(s_w)[t] =
          *reinterpret_cast<const float4*>(Wout + (size_t)(k0 + kk) * DIM + cb * 128 + c4 * 4);
    }
    __syncthreads();
#pragma unroll 8
    for (int kk = 0; kk < 64; ++kk) {
      float w = s_w[kk * 128 + c];
      acc0 += w * r0[k0 + kk];
      acc1 += w * r1[k0 + kk];
    }
  }
  float b = bout[cb * 128 + c];
  int i0 = ib * 4;
  out[(size_t)(i0 + half * 2) * DIM + cb * 128 + c]     = acc0 + b;
  out[(size_t)(i0 + half * 2 + 1) * DIM + cb * 128 + c] = acc1 + b;
}

// ---------------- launch ----------------
extern "C" void kernel_launch(void* const* d_in, const int* in_sizes, int n_in,
                              void* d_out, int out_size, void* d_ws, size_t ws_size,
                              hipStream_t stream) {
  const float* x     = (const float*)d_in[0];
  const float* pair  = (const float*)d_in[1];
  const float* rot   = (const float*)d_in[2];
  const float* trans = (const float*)d_in[3];
  const float* Wsq   = (const float*)d_in[4];
  const float* Wsk   = (const float*)d_in[5];
  const float* Wsv   = (const float*)d_in[6];
  const float* Wpq   = (const float*)d_in[7];
  const float* Wpk   = (const float*)d_in[8];
  const float* Wpv   = (const float*)d_in[9];
  const float* pw    = (const float*)d_in[10];
  const float* Wpair = (const float*)d_in[11];
  const float* bpair = (const float*)d_in[12];
  const float* Wout  = (const float*)d_in[13];
  const float* bout  = (const float*)d_in[14];
  float* out = (float*)d_out;

  float* ws = (float*)d_ws;
  float* qB = ws;                                    // 512*224
  float* kB = ws + (size_t)NTOK * QKB_STRIDE;        // 512*224
  float* vB = ws + (size_t)2 * NTOK * QKB_STRIDE;    // 512*320
  float* results = vB + (size_t)NTOK * VB_STRIDE;    // 512*1408  (total ~4.25 MB)

  ipa_proj<<<NTOK, 256, 0, stream>>>(x, rot, trans, Wsq, Wsk, Wsv, Wpq, Wpk, Wpv, qB, kB, vB);
  ipa_attn<<<NTOK, 256, 0, stream>>>(pair, rot, trans, pw, Wpair, bpair, qB, kB, vB, results);
  ipa_out<<<dim3(NTOK / 4, 3), 256, 0, stream>>>(results, Wout, bout, out);
}

// Round 2
// 451.495 us; speedup vs baseline: 1.3025x; 1.3025x over previous
//
#include <hip/hip_runtime.h>
#include <math.h>

// Invariant Point Attention, b=1, n=512, dim=384, pdim=128, H=8, SK=SV=16, PK=4, PV=8
#define NTOK 512
#define DIM 384
#define PDIM 128
#define H 8

#define QKB_STRIDE 224   // 128 scalar + 96 point (global frame)
#define VB_STRIDE  320   // 128 scalar + 192 point (global frame)
#define RES_STRIDE 1408  // 128 scalar | 192 point-local | 64 norms | 1024 pair
#define PART_STRIDE 1360 // 8 m | 8 l | 128 scalar | 192 point | 1024 pair (raw sums)

static constexpr float SCALE_SCALAR = 0.14433756729740643f; // (3*16)^-0.5
static constexpr float SCALE_POINT  = 0.13608276348795434f; // (3*4*4.5)^-0.5
static constexpr float SCALE_PAIR   = 0.57735026918962580f; // 3^-0.5

__device__ __forceinline__ float f4get(const float4& v, int k) {
  return (k == 0) ? v.x : (k == 1) ? v.y : (k == 2) ? v.z : v.w;
}

// ---------------- Kernel 1: projections + frame transform ----------------
// grid (ntok/8, 4 col-groups of 192), 192 threads. 8-token tile => 8-wide ILP.
__global__ __launch_bounds__(192) void ipa_proj(
    const float* __restrict__ x, const float* __restrict__ rot, const float* __restrict__ trans,
    const float* __restrict__ Wsq, const float* __restrict__ Wsk, const float* __restrict__ Wsv,
    const float* __restrict__ Wpq, const float* __restrict__ Wpk, const float* __restrict__ Wpv,
    float* __restrict__ qB, float* __restrict__ kB, float* __restrict__ vB)
{
  const int tt = blockIdx.x, cg = blockIdx.y, tid = threadIdx.x;
  __shared__ float s_x[8][DIM];    // 12 KB
  __shared__ float s_p[8][192];    // 6 KB
  __shared__ float s_R[8][9];
  __shared__ float s_T[8][3];

#pragma unroll
  for (int tok = 0; tok < 8; ++tok)
    for (int k = tid; k < DIM; k += 192) s_x[tok][k] = x[(size_t)(tt * 8 + tok) * DIM + k];
  if (tid < 72) s_R[tid / 9][tid % 9] = rot[(size_t)(tt * 8) * 9 + tid];
  if (tid < 24) s_T[tid / 3][tid % 3] = trans[(size_t)(tt * 8) * 3 + tid];
  __syncthreads();

  const int c = cg * 192 + tid;
  const float* W; int ncols, lc;
  if      (c < 128) { W = Wsq; ncols = 128; lc = c; }
  else if (c < 256) { W = Wsk; ncols = 128; lc = c - 128; }
  else if (c < 384) { W = Wsv; ncols = 128; lc = c - 256; }
  else if (c < 480) { W = Wpq; ncols = 96;  lc = c - 384; }
  else if (c < 576) { W = Wpk; ncols = 96;  lc = c - 480; }
  else              { W = Wpv; ncols = 192; lc = c - 576; }

  float acc[8] = {};
  const float* wp = W + lc;
#pragma unroll 4
  for (int k = 0; k < DIM; ++k) {
    float w = *wp; wp += ncols;
#pragma unroll
    for (int tok = 0; tok < 8; ++tok) acc[tok] += w * s_x[tok][k];
  }

  if (cg < 2) {
    // scalar columns: direct write (coalesced per token)
#pragma unroll
    for (int tok = 0; tok < 8; ++tok) {
      const int i = tt * 8 + tok;
      if (c < 128)      qB[(size_t)i * QKB_STRIDE + c] = acc[tok];
      else if (c < 256) kB[(size_t)i * QKB_STRIDE + (c - 128)] = acc[tok];
      else              vB[(size_t)i * VB_STRIDE + (c - 256)] = acc[tok];
    }
  } else {
    // point columns: stage then rotate/translate triples into global frame
#pragma unroll
    for (int tok = 0; tok < 8; ++tok) s_p[tok][tid] = acc[tok];
    __syncthreads();
    for (int t = tid; t < 512; t += 192) {
      const int tok = t >> 6, tr = t & 63;
      const int i = tt * 8 + tok;
      const float* R = s_R[tok];
      const float* T = s_T[tok];
      const float* src; float* dst;
      if (cg == 2) {
        if (tr < 32) { src = &s_p[tok][tr * 3];            dst = qB + (size_t)i * QKB_STRIDE + 128 + tr * 3; }
        else         { src = &s_p[tok][96 + (tr - 32) * 3]; dst = kB + (size_t)i * QKB_STRIDE + 128 + (tr - 32) * 3; }
      } else {
        src = &s_p[tok][tr * 3]; dst = vB + (size_t)i * VB_STRIDE + 128 + tr * 3;
      }
      float px = src[0], py = src[1], pz = src[2];
#pragma unroll
      for (int r = 0; r < 3; ++r)
        dst[r] = px * R[0 * 3 + r] + py * R[1 * 3 + r] + pz * R[2 * 3 + r] + T[r];
    }
  }
}

// ---------------- Kernel 2a: per-(i, j-chunk) partial attention ----------------
// grid (512, NC), 256 threads. Local softmax over the chunk; raw weighted sums out.
__global__ __launch_bounds__(256, 8) void ipa_attn_part(
    const float* __restrict__ pair, const float* __restrict__ pw,
    const float* __restrict__ Wpair, const float* __restrict__ bpair,
    const float* __restrict__ qB, const float* __restrict__ kB,
    const float* __restrict__ vB, float* __restrict__ partial,
    int NC, int JR)
{
  const int i = blockIdx.x, c = blockIdx.y, tid = threadIdx.x;
  extern __shared__ float sm[];
  float* s_attn = sm;                  // JR*12 (logits -> exp)
  float* s_red  = s_attn + JR * 12;    // 2048 (two-buffer pair reduction)
  float* s_wp   = s_red + 2048;        // 1024 [d][h]
  float* s_qs   = s_wp + 1024;         // 128
  float* s_qp   = s_qs + 128;          // 96
  float* s_coef = s_qp + 96;           // 8
  float* s_bp   = s_coef + 8;          // 8
  float* s_m    = s_bp + 8;            // 8
  float* s_l    = s_m + 8;             // 8

  for (int t = tid; t < 1024; t += 256) s_wp[t] = Wpair[t];
  if (tid < 224) {
    float v = qB[(size_t)i * QKB_STRIDE + tid];
    if (tid < 128) s_qs[tid] = v; else s_qp[tid - 128] = v;
  }
  if (tid < 8) {
    s_coef[tid] = -0.5f * log1pf(__expf(pw[tid])) * SCALE_POINT;  // softplus
    s_bp[tid]   = bpair[tid] * SCALE_PAIR;
  }
  __syncthreads();

  // ---- Phase A: logits. 2 threads per row (d-split halves), shfl_xor(1) combine ----
  {
    const int half = tid & 1;
    const int hb = half * 4;
    for (int jl = tid >> 1; jl < JR; jl += 128) {
      const int j = c * JR + jl;
      const float4* pr = reinterpret_cast<const float4*>(pair + ((size_t)i * NTOK + j) * PDIM);
      const float4* kb = reinterpret_cast<const float4*>(kB + (size_t)j * QKB_STRIDE);

      float pa[H] = {};
#pragma unroll 4
      for (int d4i = 0; d4i < 16; ++d4i) {
        const int d4 = half * 16 + d4i;
        float4 a = pr[d4];
        const float4* wp = reinterpret_cast<const float4*>(s_wp + d4 * 32);
#pragma unroll
        for (int dd = 0; dd < 4; ++dd) {
          float4 wA = wp[dd * 2], wB = wp[dd * 2 + 1];
          float xv = f4get(a, dd);
          pa[0] += xv * wA.x; pa[1] += xv * wA.y; pa[2] += xv * wA.z; pa[3] += xv * wA.w;
          pa[4] += xv * wB.x; pa[5] += xv * wB.y; pa[6] += xv * wB.z; pa[7] += xv * wB.w;
        }
      }

      float sa[4] = {};
      const float4* q4 = reinterpret_cast<const float4*>(s_qs);
#pragma unroll
      for (int t = 0; t < 16; ++t) {
        const int t4 = half * 16 + t;
        float4 q = q4[t4], k = kb[t4];
        sa[t >> 2] += q.x * k.x + q.y * k.y + q.z * k.z + q.w * k.w;
      }

      float da[4] = {};
      const float4* qp4 = reinterpret_cast<const float4*>(s_qp);
#pragma unroll
      for (int t = 0; t < 12; ++t) {
        const int t4 = half * 12 + t;
        float4 q = qp4[t4], k = kb[32 + t4];
        float d0 = q.x - k.x, d1 = q.y - k.y, d2 = q.z - k.z, d3 = q.w - k.w;
        da[t / 3] += d0 * d0 + d1 * d1 + d2 * d2 + d3 * d3;
      }

      float lg[H];
#pragma unroll
      for (int h = 0; h < H; ++h) lg[h] = pa[h] * SCALE_PAIR;
#pragma unroll
      for (int hh = 0; hh < 4; ++hh)
        lg[hb + hh] += sa[hh] * SCALE_SCALAR + s_coef[hb + hh] * da[hh];
#pragma unroll
      for (int h = 0; h < H; ++h) { float o = __shfl_xor(lg[h], 1); lg[h] += o; }
      if (half == 0) {
#pragma unroll
        for (int h = 0; h < H; ++h) s_attn[jl * 12 + h] = lg[h] + s_bp[h];
      }
    }
  }
  __syncthreads();

  // ---- Phase B: local softmax stats per head (32 lanes/head) ----
  {
    const int h = tid >> 5, l = tid & 31;
    float m = -1e30f;
    for (int k = l; k < JR; k += 32) m = fmaxf(m, s_attn[k * 12 + h]);
#pragma unroll
    for (int off = 16; off; off >>= 1) m = fmaxf(m, __shfl_xor(m, off, 32));
    float s = 0.f;
    for (int k = l; k < JR; k += 32) {
      float e = __expf(s_attn[k * 12 + h] - m);
      s_attn[k * 12 + h] = e;
      s += e;
    }
#pragma unroll
    for (int off = 16; off; off >>= 1) s += __shfl_xor(s, off, 32);
    if (l == 0) { s_m[h] = m; s_l[h] = s; }
  }
  __syncthreads();

  float* part = partial + ((size_t)i * NC + c) * PART_STRIDE;

  // ---- Phase C: raw pair aggregation (coalesced re-read, L2-hot) ----
  {
    const int g = tid >> 5, d4 = tid & 31;
    float4 acc[H];
#pragma unroll
    for (int h = 0; h < H; ++h) acc[h] = make_float4(0.f, 0.f, 0.f, 0.f);
    const float4* pb4 = reinterpret_cast<const float4*>(pair + (size_t)i * NTOK * PDIM);
    const int rpg = JR >> 3;
    for (int jl = g * rpg, e = g * rpg + rpg; jl < e; ++jl) {
      float4 pv = pb4[(size_t)(c * JR + jl) * 32 + d4];
      const float4* ar = reinterpret_cast<const float4*>(s_attn + jl * 12);
      float4 aA = ar[0], aB = ar[1];
#define FMA4(A, S) { (A).x += (S) * pv.x; (A).y += (S) * pv.y; (A).z += (S) * pv.z; (A).w += (S) * pv.w; }
      FMA4(acc[0], aA.x) FMA4(acc[1], aA.y) FMA4(acc[2], aA.z) FMA4(acc[3], aA.w)
      FMA4(acc[4], aB.x) FMA4(acc[5], aB.y) FMA4(acc[6], aB.z) FMA4(acc[7], aB.w)
#undef FMA4
    }
    // two-buffer staged reduction over 8 groups (4 rounds)
    float* buf = s_red + (g >> 2) * 1024;
    const int rnd = g & 3;
    for (int r = 0; r < 4; ++r) {
      if (rnd == r) {
        if (r == 0) {
#pragma unroll
          for (int h = 0; h < H; ++h)
            *reinterpret_cast<float4*>(buf + h * 128 + d4 * 4) = acc[h];
        } else {
#pragma unroll
          for (int h = 0; h < H; ++h) {
            float4* p = reinterpret_cast<float4*>(buf + h * 128 + d4 * 4);
            float4 v = *p;
            v.x += acc[h].x; v.y += acc[h].y; v.z += acc[h].z; v.w += acc[h].w;
            *p = v;
          }
        }
      }
      __syncthreads();
    }
    // final: buf0 + buf1 -> partial pair [h][d]
    float4 v0 = *reinterpret_cast<float4*>(s_red + tid * 4);
    float4 v1 = *reinterpret_cast<float4*>(s_red + 1024 + tid * 4);
    float4 o;
    o.x = v0.x + v1.x; o.y = v0.y + v1.y; o.z = v0.z + v1.z; o.w = v0.w + v1.w;
    *reinterpret_cast<float4*>(part + 336 + tid * 4) = o;
    if (tid < 8) { part[tid] = s_m[tid]; part[8 + tid] = s_l[tid]; }
  }

  // ---- Phase D: raw scalar/point aggregation (320 outputs) ----
  {
    const int o = tid;
    const int h0 = (o < 128) ? (o >> 4) : (o - 128) / 24;
    const int o2 = tid + 256;
    const int h1 = (tid < 64) ? (o2 - 128) / 24 : 0;
    float a0 = 0.f, a1 = 0.f;
#pragma unroll 4
    for (int jl = 0; jl < JR; ++jl) {
      const float* vr = vB + (size_t)(c * JR + jl) * VB_STRIDE;
      const float* aw = s_attn + jl * 12;
      a0 += aw[h0] * vr[o];
      if (tid < 64) a1 += aw[h1] * vr[o2];   // wave-uniform branch
    }
    if (o < 128) part[16 + o] = a0; else part[144 + (o - 128)] = a0;
    if (tid < 64) part[144 + (o2 - 128)] = a1;
  }
}

// ---------------- Kernel 2b: split-softmax combine + epilogue ----------------
__global__ __launch_bounds__(256) void ipa_combine(
    const float* __restrict__ partial, const float* __restrict__ rot,
    const float* __restrict__ trans, float* __restrict__ results, int NC)
{
  const int i = blockIdx.x, tid = threadIdx.x;
  __shared__ float s_f[4][H];
  __shared__ float s_invL[H];
  __shared__ float s_res[RES_STRIDE];
  __shared__ float s_pt[192];
  __shared__ float s_R[9], s_T[3];

  const float* pb = partial + (size_t)i * NC * PART_STRIDE;
  if (tid < H) {
    float M = -1e30f;
    for (int cc = 0; cc < NC; ++cc) M = fmaxf(M, pb[cc * PART_STRIDE + tid]);
    float L = 0.f;
    for (int cc = 0; cc < NC; ++cc) {
      float f = __expf(pb[cc * PART_STRIDE + tid] - M);
      s_f[cc][tid] = f;
      L += f * pb[cc * PART_STRIDE + 8 + tid];
    }
    s_invL[tid] = 1.f / L;
  }
  if (tid >= 32 && tid < 41) s_R[tid - 32] = rot[i * 9 + (tid - 32)];
  if (tid >= 48 && tid < 51) s_T[tid - 48] = trans[i * 3 + (tid - 48)];
  __syncthreads();

  for (int idx = tid; idx < 1344; idx += 256) {
    int h, ofs;
    if (idx < 128)      { h = idx >> 4;          ofs = 16 + idx; }
    else if (idx < 320) { h = (idx - 128) / 24;  ofs = 144 + (idx - 128); }
    else                { h = (idx - 320) >> 7;  ofs = 336 + (idx - 320); }
    float v = 0.f;
    for (int cc = 0; cc < NC; ++cc) v += s_f[cc][h] * pb[cc * PART_STRIDE + ofs];
    v *= s_invL[h];
    if (idx < 128)      s_res[idx] = v;
    else if (idx < 320) s_pt[idx - 128] = v;
    else                s_res[384 + (idx - 320)] = v;
  }
  __syncthreads();

  if (tid < 64) {
    const int h = tid >> 3, p = tid & 7;
    const int base = h * 24 + p * 3;
    float gx = s_pt[base]     - s_T[0];
    float gy = s_pt[base + 1] - s_T[1];
    float gz = s_pt[base + 2] - s_T[2];
    float lx = gx * s_R[0] + gy * s_R[1] + gz * s_R[2];
    float ly = gx * s_R[3] + gy * s_R[4] + gz * s_R[5];
    float lz = gx * s_R[6] + gy * s_R[7] + gz * s_R[8];
    s_res[128 + base]     = lx;
    s_res[128 + base + 1] = ly;
    s_res[128 + base + 2] = lz;
    s_res[320 + h * 8 + p] = sqrtf(lx * lx + ly * ly + lz * lz + 1e-8f);
  }
  __syncthreads();

  float4* dst = reinterpret_cast<float4*>(results + (size_t)i * RES_STRIDE);
  const float4* src = reinterpret_cast<const float4*>(s_res);
  for (int t = tid; t < RES_STRIDE / 4; t += 256) dst[t] = src[t];
}

// ---------------- Kernel 3: out = results @ Wout + bout (tiled) ----------------
// grid (512/16, 384/32), 256 threads: 16-token x 32-col tile, K chunks of 128.
__global__ __launch_bounds__(256) void ipa_out(
    const float* __restrict__ results, const float* __restrict__ Wout,
    const float* __restrict__ bout, float* __restrict__ out)
{
  const int tt = blockIdx.x, ct = blockIdx.y, tid = threadIdx.x;
  __shared__ float s_a[16][128];   // 8 KB
  __shared__ float s_w[128][32];   // 16 KB
  const int cc = tid & 31, tr = tid >> 5;
  float acc0 = 0.f, acc1 = 0.f;
  for (int k0 = 0; k0 < RES_STRIDE; k0 += 128) {
    __syncthreads();
    for (int t = tid; t < 512; t += 256) {
      const int tok = t >> 5, k4 = t & 31;
      reinterpret_cast<float4*>(&s_a[tok][0])[k4] =
          *reinterpret_cast<const float4*>(results + (size_t)(tt * 16 + tok) * RES_STRIDE + k0 + k4 * 4);
    }
    for (int t = tid; t < 1024; t += 256) {
      const int kk = t >> 3, c4 = t & 7;
      reinterpret_cast<float4*>(&s_w[kk][0])[c4] =
          *reinterpret_cast<const float4*>(Wout + (size_t)(k0 + kk) * DIM + ct * 32 + c4 * 4);
    }
    __syncthreads();
#pragma unroll 16
    for (int kk = 0; kk < 128; ++kk) {
      float w = s_w[kk][cc];
      acc0 += w * s_a[tr][kk];
      acc1 += w * s_a[tr + 8][kk];
    }
  }
  const float b = bout[ct * 32 + cc];
  out[(size_t)(tt * 16 + tr) * DIM + ct * 32 + cc] = acc0 + b;
  out[(size_t)(tt * 16 + tr + 8) * DIM + ct * 32 + cc] = acc1 + b;
}

// ---------------- launch ----------------
extern "C" void kernel_launch(void* const* d_in, const int* in_sizes, int n_in,
                              void* d_out, int out_size, void* d_ws, size_t ws_size,
                              hipStream_t stream) {
  const float* x     = (const float*)d_in[0];
  const float* pair  = (const float*)d_in[1];
  const float* rot   = (const float*)d_in[2];
  const float* trans = (const float*)d_in[3];
  const float* Wsq   = (const float*)d_in[4];
  const float* Wsk   = (const float*)d_in[5];
  const float* Wsv   = (const float*)d_in[6];
  const float* Wpq   = (const float*)d_in[7];
  const float* Wpk   = (const float*)d_in[8];
  const float* Wpv   = (const float*)d_in[9];
  const float* pw    = (const float*)d_in[10];
  const float* Wpair = (const float*)d_in[11];
  const float* bpair = (const float*)d_in[12];
  const float* Wout  = (const float*)d_in[13];
  const float* bout  = (const float*)d_in[14];
  float* out = (float*)d_out;

  float* ws = (float*)d_ws;
  float* qB = ws;                                     // 512*224
  float* kB = qB + (size_t)NTOK * QKB_STRIDE;         // 512*224
  float* vB = kB + (size_t)NTOK * QKB_STRIDE;         // 512*320
  float* results = vB + (size_t)NTOK * VB_STRIDE;     // 512*1408
  float* partial = results + (size_t)NTOK * RES_STRIDE;

  const size_t base_f = (size_t)NTOK * QKB_STRIDE * 2 + (size_t)NTOK * VB_STRIDE
                      + (size_t)NTOK * RES_STRIDE;
  int NC = 4;
  while (NC > 1 && (base_f + (size_t)NTOK * NC * PART_STRIDE) * 4 > ws_size) NC >>= 1;
  const int JR = NTOK / NC;
  const size_t shmem = (size_t)(JR * 12 + 2048 + 1024 + 128 + 96 + 32) * 4;

  ipa_proj<<<dim3(NTOK / 8, 4), 192, 0, stream>>>(x, rot, trans, Wsq, Wsk, Wsv, Wpq, Wpk, Wpv, qB, kB, vB);
  ipa_attn_part<<<dim3(NTOK, NC), 256, shmem, stream>>>(pair, pw, Wpair, bpair, qB, kB, vB, partial, NC, JR);
  ipa_combine<<<NTOK, 256, 0, stream>>>(partial, rot, trans, results, NC);
  ipa_out<<<dim3(NTOK / 16, DIM / 32), 256, 0, stream>>>(results, Wout, bout, out);
}